// Round 3
// baseline (2090.761 us; speedup 1.0000x reference)
//
#include <hip/hip_runtime.h>
#include <math.h>

// Problem constants
#define NB    32768
#define NDIN  1024
#define NK    4096
#define NE    128
#define NL    5
#define NH    512

// ---------------------------------------------------------------------------
// Generic fp32 GEMM: C[M,N] = op(A[M,K] @ B[K,N] + bias[N]), op = ReLU or id.
// 128x128 tile, BK=16, 256 threads, 8x8 per-thread tile (split 4+4 to keep
// LDS reads 2-way-or-less bank aliased). M%128==0, N%128==0, K%16==0.
// ---------------------------------------------------------------------------
template<bool RELU>
__global__ __launch_bounds__(256, 2)
void gemm128(const float* __restrict__ A, const float* __restrict__ Bw,
             const float* __restrict__ bias, float* __restrict__ C,
             int M, int N, int K)
{
    __shared__ float As[16][132];   // [k][m], padded stride 132 (bank spread)
    __shared__ float Bs[16][132];   // [k][n]
    const int tid = threadIdx.x;
    const int tx = tid & 15;
    const int ty = tid >> 4;
    const int m0 = blockIdx.x * 128;
    const int n0 = blockIdx.y * 128;

    // A staging: row = tid>>1 (0..127), kc = (tid&1)*8  -> 2x float4 per thread
    const int a_row = tid >> 1;
    const int a_kc  = (tid & 1) * 8;
    // B staging: k = tid>>5 (0..7, +8 second half), nc = (tid&31)*4
    const int b_k  = tid >> 5;
    const int b_nc = (tid & 31) * 4;

    const float* Ap = A  + (size_t)(m0 + a_row) * K + a_kc;
    const float* Bp = Bw + (size_t)b_k * N + n0 + b_nc;

    float acc[8][8];
#pragma unroll
    for (int i = 0; i < 8; ++i)
#pragma unroll
        for (int j = 0; j < 8; ++j) acc[i][j] = 0.f;

    for (int k0 = 0; k0 < K; k0 += 16) {
        float4 av0 = *(const float4*)(Ap + k0);
        float4 av1 = *(const float4*)(Ap + k0 + 4);
        float4 bv0 = *(const float4*)(Bp + (size_t)k0 * N);
        float4 bv1 = *(const float4*)(Bp + (size_t)(k0 + 8) * N);
        __syncthreads();   // previous tile's compute done before overwrite
        As[a_kc + 0][a_row] = av0.x;
        As[a_kc + 1][a_row] = av0.y;
        As[a_kc + 2][a_row] = av0.z;
        As[a_kc + 3][a_row] = av0.w;
        As[a_kc + 4][a_row] = av1.x;
        As[a_kc + 5][a_row] = av1.y;
        As[a_kc + 6][a_row] = av1.z;
        As[a_kc + 7][a_row] = av1.w;
        *(float4*)&Bs[b_k    ][b_nc] = bv0;
        *(float4*)&Bs[b_k + 8][b_nc] = bv1;
        __syncthreads();
#pragma unroll
        for (int kk = 0; kk < 16; ++kk) {
            float a[8], b[8];
            *(float4*)&a[0] = *(const float4*)&As[kk][ty * 4];
            *(float4*)&a[4] = *(const float4*)&As[kk][64 + ty * 4];
            *(float4*)&b[0] = *(const float4*)&Bs[kk][tx * 4];
            *(float4*)&b[4] = *(const float4*)&Bs[kk][64 + tx * 4];
#pragma unroll
            for (int i = 0; i < 8; ++i)
#pragma unroll
                for (int j = 0; j < 8; ++j)
                    acc[i][j] = fmaf(a[i], b[j], acc[i][j]);
        }
    }

    // epilogue: bias + optional relu, coalesced float4 stores
    float bb[8];
    *(float4*)&bb[0] = *(const float4*)(bias + n0 + tx * 4);
    *(float4*)&bb[4] = *(const float4*)(bias + n0 + 64 + tx * 4);
#pragma unroll
    for (int rg = 0; rg < 2; ++rg) {
#pragma unroll
        for (int i = 0; i < 4; ++i) {
            const size_t row = (size_t)(m0 + rg * 64 + ty * 4 + i);
#pragma unroll
            for (int cg = 0; cg < 2; ++cg) {
                float4 o;
                o.x = acc[rg * 4 + i][cg * 4 + 0] + bb[cg * 4 + 0];
                o.y = acc[rg * 4 + i][cg * 4 + 1] + bb[cg * 4 + 1];
                o.z = acc[rg * 4 + i][cg * 4 + 2] + bb[cg * 4 + 2];
                o.w = acc[rg * 4 + i][cg * 4 + 3] + bb[cg * 4 + 3];
                if (RELU) {
                    o.x = fmaxf(o.x, 0.f); o.y = fmaxf(o.y, 0.f);
                    o.z = fmaxf(o.z, 0.f); o.w = fmaxf(o.w, 0.f);
                }
                *(float4*)(C + row * N + n0 + cg * 64 + tx * 4) = o;
            }
        }
    }
}

// ---------------------------------------------------------------------------
// Normalize protos and write TRANSPOSED: pronT[e][k] = protos[k][e]/max(|row|,eps)
// One wave per proto row.
// ---------------------------------------------------------------------------
__global__ __launch_bounds__(256)
void proto_norm_t(const float* __restrict__ protos, float* __restrict__ pronT)
{
    const int wave = threadIdx.x >> 6, lane = threadIdx.x & 63;
    const int k = blockIdx.x * 4 + wave;
    float2 v = *(const float2*)(protos + (size_t)k * NE + lane * 2);
    float ss = v.x * v.x + v.y * v.y;
#pragma unroll
    for (int off = 32; off; off >>= 1) ss += __shfl_xor(ss, off);
    const float inv = 1.0f / fmaxf(sqrtf(ss), 1e-8f);
    pronT[(size_t)(lane * 2    ) * NK + k] = v.x * inv;
    pronT[(size_t)(lane * 2 + 1) * NK + k] = v.y * inv;
}

// ---------------------------------------------------------------------------
// Fused: logits = 10 * cos_sim(encoded, protos); softmax -> probs (out);
// argmax -> gather raw proto -> ai = [encoded, best_proto] (ws).
// Block: 512 threads (8 waves) = 8 batch rows; thread owns 8 consecutive
// proto columns (cols = tid*8..tid*8+7); sims live in 64 registers.
// pronT is [E][K] so proto loads are fully coalesced full-line reads.
// ---------------------------------------------------------------------------
__global__ __launch_bounds__(512, 2)
void sims_softmax_ai(const float* __restrict__ enc,    // [B,128] raw encoded
                     const float* __restrict__ pronT,  // [128,4096] normalized^T
                     const float* __restrict__ protos, // [4096,128] raw
                     float* __restrict__ probs,        // [B,4096] out
                     float* __restrict__ ai)           // [B,256]  ws
{
    __shared__ float encs[8][128];
    __shared__ float scale_s[8];
    __shared__ float redv[8][8];   // [wave][row]
    __shared__ int   redi[8][8];
    __shared__ float rowmax[8];
    __shared__ float rowsum[8];
    __shared__ int   rowidx[8];

    const int tid  = threadIdx.x;
    const int wave = tid >> 6, lane = tid & 63;
    const size_t r0 = (size_t)blockIdx.x * 8;

    // stage 8 encoded rows + per-row scale = 10/max(|enc|,eps)
    {
        float2 v = *(const float2*)(enc + (r0 + wave) * NE + lane * 2);
        encs[wave][lane * 2]     = v.x;
        encs[wave][lane * 2 + 1] = v.y;
        float ss = v.x * v.x + v.y * v.y;
#pragma unroll
        for (int off = 32; off; off >>= 1) ss += __shfl_xor(ss, off);
        if (lane == 0) scale_s[wave] = 10.0f / fmaxf(sqrtf(ss), 1e-8f);
    }
    __syncthreads();

    const int c0 = tid * 8;            // this thread's 8 proto columns
    float acc[8][8];
#pragma unroll
    for (int r = 0; r < 8; ++r)
#pragma unroll
        for (int j = 0; j < 8; ++j) acc[r][j] = 0.f;

#pragma unroll 2
    for (int e0 = 0; e0 < 128; e0 += 4) {
        float4 p[4][2];
#pragma unroll
        for (int e = 0; e < 4; ++e) {
            p[e][0] = *(const float4*)(pronT + (size_t)(e0 + e) * NK + c0);
            p[e][1] = *(const float4*)(pronT + (size_t)(e0 + e) * NK + c0 + 4);
        }
#pragma unroll
        for (int r = 0; r < 8; ++r) {
            float4 a = *(const float4*)&encs[r][e0];   // broadcast read
            acc[r][0] += a.x*p[0][0].x + a.y*p[1][0].x + a.z*p[2][0].x + a.w*p[3][0].x;
            acc[r][1] += a.x*p[0][0].y + a.y*p[1][0].y + a.z*p[2][0].y + a.w*p[3][0].y;
            acc[r][2] += a.x*p[0][0].z + a.y*p[1][0].z + a.z*p[2][0].z + a.w*p[3][0].z;
            acc[r][3] += a.x*p[0][0].w + a.y*p[1][0].w + a.z*p[2][0].w + a.w*p[3][0].w;
            acc[r][4] += a.x*p[0][1].x + a.y*p[1][1].x + a.z*p[2][1].x + a.w*p[3][1].x;
            acc[r][5] += a.x*p[0][1].y + a.y*p[1][1].y + a.z*p[2][1].y + a.w*p[3][1].y;
            acc[r][6] += a.x*p[0][1].z + a.y*p[1][1].z + a.z*p[2][1].z + a.w*p[3][1].z;
            acc[r][7] += a.x*p[0][1].w + a.y*p[1][1].w + a.z*p[2][1].w + a.w*p[3][1].w;
        }
    }

    // logits = acc * scale[row]; per-thread max/argmax (first-occurrence ties)
    float bmax[8]; int bidx[8];
#pragma unroll
    for (int r = 0; r < 8; ++r) {
        const float sc = scale_s[r];
        bmax[r] = -INFINITY; bidx[r] = 0;
#pragma unroll
        for (int j = 0; j < 8; ++j) {
            float v = acc[r][j] * sc;
            acc[r][j] = v;
            if (v > bmax[r]) { bmax[r] = v; bidx[r] = c0 + j; }
        }
    }
    // wave-level (val,idx) reduce: higher val, tie -> lower idx
#pragma unroll
    for (int off = 32; off; off >>= 1) {
#pragma unroll
        for (int r = 0; r < 8; ++r) {
            float ov = __shfl_xor(bmax[r], off);
            int   oi = __shfl_xor(bidx[r], off);
            if (ov > bmax[r] || (ov == bmax[r] && oi < bidx[r])) { bmax[r] = ov; bidx[r] = oi; }
        }
    }
    if (lane == 0)
#pragma unroll
        for (int r = 0; r < 8; ++r) { redv[wave][r] = bmax[r]; redi[wave][r] = bidx[r]; }
    __syncthreads();
    if (tid < 8) {   // one thread per row: reduce across 8 waves
        float mv = redv[0][tid]; int mi = redi[0][tid];
#pragma unroll
        for (int w = 1; w < 8; ++w) {
            float v = redv[w][tid]; int i = redi[w][tid];
            if (v > mv || (v == mv && i < mi)) { mv = v; mi = i; }
        }
        rowmax[tid] = mv; rowidx[tid] = mi;
    }
    __syncthreads();

    // exp + sum
    float lsum[8];
#pragma unroll
    for (int r = 0; r < 8; ++r) {
        const float m = rowmax[r];
        float s = 0.f;
#pragma unroll
        for (int j = 0; j < 8; ++j) {
            float pv = expf(acc[r][j] - m);
            acc[r][j] = pv;
            s += pv;
        }
        lsum[r] = s;
    }
#pragma unroll
    for (int off = 32; off; off >>= 1)
#pragma unroll
        for (int r = 0; r < 8; ++r) lsum[r] += __shfl_xor(lsum[r], off);
    if (lane == 0)
#pragma unroll
        for (int r = 0; r < 8; ++r) redv[wave][r] = lsum[r];
    __syncthreads();
    if (tid < 8) {
        float s = 0.f;
#pragma unroll
        for (int w = 0; w < 8; ++w) s += redv[w][tid];
        rowsum[tid] = s;
    }
    __syncthreads();

    // write probs (coalesced: thread t owns bytes [t*32, t*32+32) of each row)
#pragma unroll
    for (int r = 0; r < 8; ++r) {
        const float inv = 1.0f / rowsum[r];
        float4 o0, o1;
        o0.x = acc[r][0]*inv; o0.y = acc[r][1]*inv; o0.z = acc[r][2]*inv; o0.w = acc[r][3]*inv;
        o1.x = acc[r][4]*inv; o1.y = acc[r][5]*inv; o1.z = acc[r][6]*inv; o1.w = acc[r][7]*inv;
        float* op = probs + (r0 + r) * NK + c0;
        *(float4*)(op)     = o0;
        *(float4*)(op + 4) = o1;
    }

    // ai = [encoded_row, protos[best_idx]] ; wave w handles row w
    {
        const int bi = rowidx[wave];
        float4 v;
        if (lane < 32) v = *(const float4*)&encs[wave][lane * 4];
        else           v = *(const float4*)(protos + (size_t)bi * NE + (lane - 32) * 4);
        *(float4*)(ai + (r0 + wave) * (2 * NE) + lane * 4) = v;
    }
}

// ---------------------------------------------------------------------------
// hierarchy: out[b][l] = sigmoid(ai[b] . Wh[l] + bh[l]); one wave per row.
// ---------------------------------------------------------------------------
__global__ __launch_bounds__(256)
void hier_kernel(const float* __restrict__ ai, const float* __restrict__ Wh,
                 const float* __restrict__ bh, float* __restrict__ out)
{
    __shared__ float wh_s[NL * 2 * NE];
    const int tid = threadIdx.x;
    for (int i = tid; i < NL * 2 * NE; i += 256) wh_s[i] = Wh[i];
    __syncthreads();
    const int wave = tid >> 6, lane = tid & 63;
    const size_t row = (size_t)blockIdx.x * 4 + wave;
    float4 a = *(const float4*)(ai + row * (2 * NE) + lane * 4);
    float s[NL];
#pragma unroll
    for (int l = 0; l < NL; ++l) {
        float4 w = *(const float4*)&wh_s[l * 2 * NE + lane * 4];
        s[l] = a.x * w.x + a.y * w.y + a.z * w.z + a.w * w.w;
    }
#pragma unroll
    for (int off = 32; off; off >>= 1)
#pragma unroll
        for (int l = 0; l < NL; ++l) s[l] += __shfl_xor(s[l], off);
    if (lane == 0) {
#pragma unroll
        for (int l = 0; l < NL; ++l) {
            float x = s[l] + bh[l];
            out[row * NL + l] = 1.0f / (1.0f + expf(-x));
        }
    }
}

// ---------------------------------------------------------------------------
extern "C" void kernel_launch(void* const* d_in, const int* in_sizes, int n_in,
                              void* d_out, int out_size, void* d_ws, size_t ws_size,
                              hipStream_t stream)
{
    const float* X      = (const float*)d_in[0];
    const float* W1     = (const float*)d_in[1];
    const float* b1     = (const float*)d_in[2];
    const float* W2     = (const float*)d_in[3];
    const float* b2     = (const float*)d_in[4];
    const float* protos = (const float*)d_in[5];
    const float* W3     = (const float*)d_in[6];
    const float* b3     = (const float*)d_in[7];
    const float* W4     = (const float*)d_in[8];
    const float* b4     = (const float*)d_in[9];
    const float* Wh     = (const float*)d_in[10];
    const float* bh     = (const float*)d_in[11];

    float* out_probs = (float*)d_out;                          // [B,K]
    float* out_abs   = out_probs + (size_t)NB * NK;            // [B,E]
    float* out_hier  = out_abs   + (size_t)NB * NE;            // [B,L]

    float* ws    = (float*)d_ws;
    float* H1    = ws;                                         // [B,512] (dies after gemm2)
    float* ai    = ws;                                         // [B,256] reuses H1 region
    float* T     = ws + (size_t)NB * (2 * NE);                 // [B,128] inside H1 region
    float* enc   = ws + (size_t)NB * NH;                       // [B,128]
    float* pronT = enc + (size_t)NB * NE;                      // [128,4096]

    // 1. normalized, transposed protos
    proto_norm_t<<<NK / 4, 256, 0, stream>>>(protos, pronT);
    // 2. H1 = relu(X@W1 + b1)
    gemm128<true ><<<dim3(NB / 128, NH / 128), 256, 0, stream>>>(X, W1, b1, H1, NB, NH, NDIN);
    // 3. enc = H1@W2 + b2
    gemm128<false><<<dim3(NB / 128, 1), 256, 0, stream>>>(H1, W2, b2, enc, NB, NE, NH);
    // 4. fused sims/softmax/argmax/ai
    sims_softmax_ai<<<NB / 8, 512, 0, stream>>>(enc, pronT, protos, out_probs, ai);
    // 5. T = relu(ai@W3 + b3)
    gemm128<true ><<<dim3(NB / 128, 1), 256, 0, stream>>>(ai, W3, b3, T, NB, NE, 2 * NE);
    // 6. abstraction = T@W4 + b4
    gemm128<false><<<dim3(NB / 128, 1), 256, 0, stream>>>(T, W4, b4, out_abs, NB, NE, NE);
    // 7. hierarchy
    hier_kernel<<<NB / 4, 256, 0, stream>>>(ai, Wh, bh, out_hier);
}